// Round 20
// baseline (450.742 us; speedup 1.0000x reference)
//
#include <hip/hip_runtime.h>
#include <stdint.h>

typedef unsigned short u16;
typedef short bf16x8 __attribute__((ext_vector_type(8)));
typedef short bf16x4 __attribute__((ext_vector_type(4)));
typedef float f32x4 __attribute__((ext_vector_type(4)));
typedef u16 u16x4 __attribute__((ext_vector_type(4)));

__device__ __forceinline__ u16 f2bf(float f) {
  union { float f; unsigned int u; } v; v.f = f;
  unsigned int r = v.u + 0x7fffu + ((v.u >> 16) & 1u);
  return (u16)(r >> 16);
}

__device__ __forceinline__ void async16(const void* g, void* l) {
  __builtin_amdgcn_global_load_lds(
      (const __attribute__((address_space(1))) unsigned int*)g,
      (__attribute__((address_space(3))) unsigned int*)l, 16, 0, 0);
}

__device__ __forceinline__ f32x4 mfma16x16(bf16x4 a, bf16x4 b, f32x4 c) {
#if __has_builtin(__builtin_amdgcn_mfma_f32_16x16x16bf16_1k)
  return __builtin_amdgcn_mfma_f32_16x16x16bf16_1k(a, b, c, 0, 0, 0);
#else
  asm volatile("v_mfma_f32_16x16x16_bf16 %0, %1, %2, %0\n\ts_nop 7\n\ts_nop 7"
               : "+v"(c) : "v"(a), "v"(b));
  return c;
#endif
}

// ---------------- front kernel: pose MLP + x cast + both weight transposes
__global__ void __launch_bounds__(256) front_kernel(
    const float4* __restrict__ x4, u16x4* __restrict__ xh4,
    const float* __restrict__ ang, const float* __restrict__ W1,
    const float* __restrict__ b1, const float* __restrict__ W2,
    const float* __restrict__ b2, float* __restrict__ pose,
    const float* __restrict__ Wqkv, u16* __restrict__ wqkvt,
    const float* __restrict__ Wproj, u16* __restrict__ wprojt) {
  __shared__ float sh[64 * 65];
  const int fb = blockIdx.x, t = threadIdx.x;
  if (fb < 96) {
    float (*hid)[64] = (float (*)[64])sh;
    for (int idx = t; idx < 512; idx += 256) {
      int b = idx >> 6, j = idx & 63;
      float a = b1[j];
#pragma unroll
      for (int i = 0; i < 3; ++i) a += ang[b * 3 + i] * W1[i * 64 + j];
      hid[b][j] = fmaxf(a, 0.f);
    }
    __syncthreads();
    int idx = fb * 256 + t;
    int b = idx / 3072, c = idx - b * 3072;
    float a = b2[c];
#pragma unroll
    for (int j = 0; j < 64; ++j) a += hid[b][j] * W2[j * 3072 + c];
    pose[idx] = a;
  } else if (fb < 1120) {
    const int n4 = 8 * 1024 * 1024 / 4;
    int i = (fb - 96) * 256 + t;
    const int stride = 1024 * 256;
    for (; i < n4; i += stride) {
      float4 v = x4[i];
      u16x4 o;
      o[0] = f2bf(v.x); o[1] = f2bf(v.y); o[2] = f2bf(v.z); o[3] = f2bf(v.w);
      xh4[i] = o;
    }
  } else {
    const float* W; u16* Wt; int Kdim, Ncol, bx, by;
    if (fb < 1888) { W = Wqkv; Wt = wqkvt; Kdim = 1024; Ncol = 3072;
                     int b = fb - 1120; bx = b % 48; by = b / 48; }
    else           { W = Wproj; Wt = wprojt; Kdim = 1024; Ncol = 1024;
                     int b = fb - 1888; bx = b % 16; by = b / 16; }
    float (*tile)[65] = (float (*)[65])sh;
    const int tx = t & 63, ty = t >> 6;
    const int c0 = bx * 64, k0 = by * 64;
#pragma unroll
    for (int rr = 0; rr < 16; ++rr) {
      int row = rr * 4 + ty;
      tile[row][tx] = W[(size_t)(k0 + row) * Ncol + c0 + tx];
    }
    __syncthreads();
#pragma unroll
    for (int rr = 0; rr < 16; ++rr) {
      int row = rr * 4 + ty;
      Wt[(size_t)(c0 + row) * Kdim + k0 + tx] = f2bf(tile[tx][row]);
    }
  }
}

// ---------------- QKV GEMM (r12, measured best: 99 us): 256x128, dbuf 96KB,
// 2-phase counted vmcnt(2), T2 XOR swizzle, L2 2D-XCD chunk. Grid 768.
__global__ void __launch_bounds__(512) gemm8_kernel(
    const u16* __restrict__ A, const u16* __restrict__ Bt,
    const float* __restrict__ bias, const float* __restrict__ pose,
    u16* __restrict__ qout, u16* __restrict__ kout, u16* __restrict__ vtout,
    int Kdim) {
  constexpr int BOFF = 256 * 64;
  __shared__ u16 lds[2][(256 + 128) * 64];
  const int t = threadIdx.x, l = t & 63, w = t >> 6;
  const int g = l >> 4, r16 = l & 15;
  const int wr = w >> 1, wc = w & 1;
  const int xk = r16 & 7;
  const int blk = blockIdx.x;
  const int xcd = blk & 7, c = blk >> 3;
  const int m0 = (xcd * 4 + (c & 3)) * 256;
  const int n0 = (c >> 2) * 128;
  const u16* Ab = A + (size_t)m0 * Kdim;
  const u16* Bb = Bt + (size_t)n0 * Kdim;

  auto stage = [&](int buf, int kt, int st) {
#pragma unroll
    for (int it = 0; it < 2; ++it) {
      int idx = it * 512 + t, row = idx >> 3;
      int seg = (idx & 7) ^ (row & 7);
      if (st < 2)
        async16(Ab + (size_t)(st * 128 + row) * Kdim + kt + seg * 8,
                &lds[buf][st * 128 * 64 + idx * 8]);
      else
        async16(Bb + (size_t)row * Kdim + kt + seg * 8, &lds[buf][BOFF + idx * 8]);
    }
  };

  f32x4 acc[4][4] = {};
  const int nT = Kdim >> 6;
#pragma unroll
  for (int st = 0; st < 3; ++st) stage(0, 0, st);

  for (int tt = 0; tt < nT; ++tt) {
    const int cur = tt & 1, nxt = cur ^ 1;
    const bool pf = (tt + 1 < nT);
    const int ktn = (tt + 1) << 6;
    if (pf) {
      stage(nxt, ktn, 0);
      __builtin_amdgcn_sched_barrier(0);
      asm volatile("s_waitcnt vmcnt(2)" ::: "memory");
    } else {
      asm volatile("s_waitcnt vmcnt(0)" ::: "memory");
    }
    __builtin_amdgcn_s_barrier();
    __builtin_amdgcn_sched_barrier(0);
    bf16x8 bfr[4][2], af[2][2];
#pragma unroll
    for (int nj = 0; nj < 4; ++nj)
#pragma unroll
      for (int ks = 0; ks < 2; ++ks)
        bfr[nj][ks] = *(const bf16x8*)&lds[cur][BOFF + (wc * 64 + nj * 16 + r16) * 64 +
                                               ((ks * 4 + g) ^ xk) * 8];
#pragma unroll
    for (int mi = 0; mi < 2; ++mi)
#pragma unroll
      for (int ks = 0; ks < 2; ++ks)
        af[mi][ks] = *(const bf16x8*)&lds[cur][(wr * 64 + mi * 16 + r16) * 64 +
                                              ((ks * 4 + g) ^ xk) * 8];
    __builtin_amdgcn_s_setprio(1);
#pragma unroll
    for (int ks = 0; ks < 2; ++ks)
#pragma unroll
      for (int mi = 0; mi < 2; ++mi)
#pragma unroll
        for (int nj = 0; nj < 4; ++nj)
          acc[mi][nj] = __builtin_amdgcn_mfma_f32_16x16x32_bf16(af[mi][ks], bfr[nj][ks],
                                                                acc[mi][nj], 0, 0, 0);
    __builtin_amdgcn_s_setprio(0);
    if (pf) { stage(nxt, ktn, 1); stage(nxt, ktn, 2); }
    bf16x8 af2[2][2];
#pragma unroll
    for (int mi = 0; mi < 2; ++mi)
#pragma unroll
      for (int ks = 0; ks < 2; ++ks)
        af2[mi][ks] = *(const bf16x8*)&lds[cur][(wr * 64 + (mi + 2) * 16 + r16) * 64 +
                                               ((ks * 4 + g) ^ xk) * 8];
    __builtin_amdgcn_s_setprio(1);
#pragma unroll
    for (int ks = 0; ks < 2; ++ks)
#pragma unroll
      for (int mi = 0; mi < 2; ++mi)
#pragma unroll
        for (int nj = 0; nj < 4; ++nj)
          acc[mi + 2][nj] = __builtin_amdgcn_mfma_f32_16x16x32_bf16(af2[mi][ks], bfr[nj][ks],
                                                                    acc[mi + 2][nj], 0, 0, 0);
    __builtin_amdgcn_s_setprio(0);
    __builtin_amdgcn_s_barrier();
  }

#pragma unroll
  for (int mi = 0; mi < 4; ++mi)
#pragma unroll
    for (int nj = 0; nj < 4; ++nj)
#pragma unroll
      for (int r = 0; r < 4; ++r) {
        int row = m0 + wr * 64 + mi * 16 + g * 4 + r;
        int col = n0 + wc * 64 + nj * 16 + r16;
        float v = acc[mi][nj][r] + bias[col];
        int b = row >> 10, n = row & 1023;
        v += pose[b * 3072 + col];
        u16 hv = f2bf(v);
        int three = col >> 10, hh = (col >> 6) & 15, d = col & 63;
        size_t bhh = (size_t)(b * 16 + hh);
        if (three == 0)      qout[(bhh * 1024 + n) * 64 + d] = hv;
        else if (three == 1) kout[(bhh * 1024 + n) * 64 + d] = hv;
        else                 vtout[(bhh * 64 + d) * 1024 + n] = hv;
      }
}

// ---------------- proj GEMM (r13, measured best): 128x128 m97-style,
// single-buffer 32KB, 256 thr, 512 blocks high TLP, T2 swizzle + L2 chunk.
__global__ void __launch_bounds__(256) gemm97_kernel(
    const u16* __restrict__ A, const u16* __restrict__ Bt,
    const float* __restrict__ bias, float* __restrict__ cout,
    int Kdim, int Ncols) {
  __shared__ u16 ldsA[128 * 64];
  __shared__ u16 ldsB[128 * 64];
  const int t = threadIdx.x, l = t & 63, w = t >> 6;
  const int g = l >> 4, r16 = l & 15;
  const int wr = w >> 1, wc = w & 1;
  const int xk = r16 & 7;
  const int blk = blockIdx.x;
  const int xcd = blk & 7, c = blk >> 3;
  const int m0 = (xcd * 8 + (c & 7)) * 128;
  const int n0 = (c >> 3) * 128;
  const u16* Ab = A + (size_t)m0 * Kdim;
  const u16* Bb = Bt + (size_t)n0 * Kdim;

  f32x4 acc[4][4] = {};
  for (int kt = 0; kt < Kdim; kt += 64) {
#pragma unroll
    for (int ii = 0; ii < 4; ++ii) {
      int idx = ii * 256 + t, row = idx >> 3;
      int seg = (idx & 7) ^ (row & 7);
      async16(Ab + (size_t)row * Kdim + kt + seg * 8, &ldsA[idx * 8]);
    }
#pragma unroll
    for (int ii = 0; ii < 4; ++ii) {
      int idx = ii * 256 + t, row = idx >> 3;
      int seg = (idx & 7) ^ (row & 7);
      async16(Bb + (size_t)row * Kdim + kt + seg * 8, &ldsB[idx * 8]);
    }
    __syncthreads();
#pragma unroll
    for (int ks = 0; ks < 2; ++ks) {
      bf16x8 a[4], bb[4];
#pragma unroll
      for (int i = 0; i < 4; ++i)
        a[i] = *(const bf16x8*)&ldsA[(wr * 64 + i * 16 + r16) * 64 + ((ks * 4 + g) ^ xk) * 8];
#pragma unroll
      for (int j = 0; j < 4; ++j)
        bb[j] = *(const bf16x8*)&ldsB[(wc * 64 + j * 16 + r16) * 64 + ((ks * 4 + g) ^ xk) * 8];
#pragma unroll
      for (int i = 0; i < 4; ++i)
#pragma unroll
        for (int j = 0; j < 4; ++j)
          acc[i][j] = __builtin_amdgcn_mfma_f32_16x16x32_bf16(a[i], bb[j], acc[i][j], 0, 0, 0);
    }
    __syncthreads();
  }

#pragma unroll
  for (int i = 0; i < 4; ++i)
#pragma unroll
    for (int j = 0; j < 4; ++j)
#pragma unroll
      for (int r = 0; r < 4; ++r) {
        int row = m0 + wr * 64 + i * 16 + g * 4 + r;
        int col = n0 + wc * 64 + j * 16 + r16;
        cout[(size_t)row * Ncols + col] = acc[i][j][r] + bias[col];
      }
}

// ---------------- attention r20: NO-LDS (m169 / Common-mistake #7).
// K/V are L2-resident per XCD (bh=blk&127 remap); MFMA fragments read
// DIRECTLY from global: K-frag = 2KB coalesced per wave-instr; V-frags
// aggregate to full lines across the s4 loop. Zero LDS, zero barriers --
// waves fully independent (max TLP). Softmax pipeline = r18/r19-proven
// (defer-max, fma-fold exp2, deferred row-sum, scalar f2bf).
// 64 q-rows/block (16/wave), grid 2048.
__global__ void __launch_bounds__(256) attn_kernel(
    const u16* __restrict__ Qb, const u16* __restrict__ Kb,
    const u16* __restrict__ Vtb, u16* __restrict__ aout) {
  const int t = threadIdx.x, l = t & 63, w = t >> 6;
  const int g = l >> 4, r16 = l & 15;
  const int blk = blockIdx.x;
  const int bh = blk & 127, qt = blk >> 7;   // XCD-locality remap
  const int b = bh >> 4, h = bh & 15;
  const int q0 = qt * 64 + w * 16;
  const u16* Qp = Qb + ((size_t)bh * 1024 + q0 + r16) * 64;
  bf16x8 qreg0 = *(const bf16x8*)(Qp + g * 8);
  bf16x8 qreg1 = *(const bf16x8*)(Qp + 32 + g * 8);
  const u16* Kbase = Kb + (size_t)bh * 1024 * 64;
  const u16* Vbase = Vtb + (size_t)bh * 64 * 1024;
  const float cexp = 0.18033688f;            // 0.125 * log2(e)

  float m = -3e38f, rs = 0.f;
  f32x4 o[4] = {};
  for (int kt = 0; kt < 16; ++kt) {
    const int key0 = kt * 64;
    // ---- QK^T (swapped): K-frags direct from global (L2-hot, coalesced)
    f32x4 s[4] = {};
#pragma unroll
    for (int f = 0; f < 4; ++f) {
      const u16* kr = Kbase + (size_t)(key0 + f * 16 + r16) * 64;
      bf16x8 ak0 = *(const bf16x8*)(kr + g * 8);
      s[f] = __builtin_amdgcn_mfma_f32_16x16x32_bf16(ak0, qreg0, s[f], 0, 0, 0);
      bf16x8 ak1 = *(const bf16x8*)(kr + 32 + g * 8);
      s[f] = __builtin_amdgcn_mfma_f32_16x16x32_bf16(ak1, qreg1, s[f], 0, 0, 0);
    }
    float mt = -3e38f;
#pragma unroll
    for (int f = 0; f < 4; ++f) {
      float m01 = fmaxf(s[f][0], s[f][1]);
      float m23 = fmaxf(s[f][2], s[f][3]);
      mt = fmaxf(mt, fmaxf(m01, m23));
    }
    mt = fmaxf(mt, __shfl_xor(mt, 16));
    mt = fmaxf(mt, __shfl_xor(mt, 32));
    if (!__all(mt - m <= 64.f)) {
      float mnew = fmaxf(m, mt);
      float alpha = exp2f((m - mnew) * cexp);
      float ar[4];
#pragma unroll
      for (int r = 0; r < 4; ++r) ar[r] = __shfl(alpha, (l & 48) | (g * 4 + r));
#pragma unroll
      for (int nf = 0; nf < 4; ++nf)
#pragma unroll
        for (int r = 0; r < 4; ++r) o[nf][r] *= ar[r];
      rs *= alpha;                            // per-lane partial, exact
      m = mnew;
    }
    const float nmc = -m * cexp;
    float rt = 0.f;
    bf16x4 pa[4];
#pragma unroll
    for (int f = 0; f < 4; ++f) {
#pragma unroll
      for (int r = 0; r < 4; ++r) {
        float p = exp2f(fmaf(s[f][r], cexp, nmc));
        rt += p;
        pa[f][r] = (short)f2bf(p);
      }
    }
    rs += rt;                                 // deferred cross-lane reduce
    // ---- PV: V-frags direct from global (V^T layout, L2-hot)
#pragma unroll
    for (int s4 = 0; s4 < 4; ++s4)
#pragma unroll
      for (int nf = 0; nf < 4; ++nf) {
        bf16x4 bv = *(const bf16x4*)(Vbase + (size_t)(nf * 16 + r16) * 1024 +
                                     key0 + s4 * 16 + g * 4);
        o[nf] = mfma16x16(pa[s4], bv, o[nf]);
      }
  }
  rs += __shfl_xor(rs, 16);
  rs += __shfl_xor(rs, 32);
  float rr[4];
#pragma unroll
  for (int r = 0; r < 4; ++r) rr[r] = __shfl(1.0f / rs, (l & 48) | (g * 4 + r));
#pragma unroll
  for (int nf = 0; nf < 4; ++nf)
#pragma unroll
    for (int r = 0; r < 4; ++r) {
      int qq = q0 + g * 4 + r;
      int d = nf * 16 + r16;
      aout[((size_t)b * 1024 + qq) * 1024 + h * 64 + d] = f2bf(o[nf][r] * rr[r]);
    }
}

extern "C" void kernel_launch(void* const* d_in, const int* in_sizes, int n_in,
                              void* d_out, int out_size, void* d_ws, size_t ws_size,
                              hipStream_t stream) {
  (void)in_sizes; (void)n_in; (void)out_size; (void)ws_size;
  const float* x     = (const float*)d_in[0];
  const float* ang   = (const float*)d_in[1];
  const float* Wqkv  = (const float*)d_in[2];
  const float* bqkv  = (const float*)d_in[3];
  const float* W1    = (const float*)d_in[4];
  const float* b1    = (const float*)d_in[5];
  const float* W2    = (const float*)d_in[6];
  const float* b2    = (const float*)d_in[7];
  const float* Wproj = (const float*)d_in[8];
  const float* bproj = (const float*)d_in[9];
  float* out = (float*)d_out;
  char* ws = (char*)d_ws;

  u16* xh     = (u16*)(ws);                                 // 16 MB; reused as attn_out
  u16* wqkvt  = (u16*)(ws + (size_t)16 * 1024 * 1024);      // 6 MB
  u16* wprojt = (u16*)(ws + (size_t)22 * 1024 * 1024);      // 2 MB
  float* pose = (float*)(ws + (size_t)24 * 1024 * 1024);    // 96 KB
  u16* Qb     = (u16*)(ws + (size_t)25 * 1024 * 1024);      // 16 MB
  u16* Kb     = (u16*)(ws + (size_t)41 * 1024 * 1024);      // 16 MB
  u16* Vtb    = (u16*)(ws + (size_t)57 * 1024 * 1024);      // 16 MB

  front_kernel<<<2144, 256, 0, stream>>>((const float4*)x, (u16x4*)xh,
                                         ang, W1, b1, W2, b2, pose,
                                         Wqkv, wqkvt, Wproj, wprojt);
  gemm8_kernel<<<768, 512, 0, stream>>>(xh, wqkvt, bqkv, pose,
                                        Qb, Kb, Vtb, 1024);
  // attn: no-LDS, 16 q-tiles x 128 bh = 2048 blocks
  attn_kernel<<<2048, 256, 0, stream>>>(Qb, Kb, Vtb, xh);
  gemm97_kernel<<<512, 256, 0, stream>>>(xh, wprojt, bproj, out, 1024, 1024);
}

// Round 21
// 193.968 us; speedup vs baseline: 2.3238x; 2.3238x over previous
//
#include <hip/hip_runtime.h>
#include <stdint.h>

typedef unsigned short u16;
typedef short bf16x8 __attribute__((ext_vector_type(8)));
typedef short bf16x4 __attribute__((ext_vector_type(4)));
typedef float f32x4 __attribute__((ext_vector_type(4)));
typedef u16 u16x4 __attribute__((ext_vector_type(4)));

__device__ __forceinline__ u16 f2bf(float f) {
  union { float f; unsigned int u; } v; v.f = f;
  unsigned int r = v.u + 0x7fffu + ((v.u >> 16) & 1u);
  return (u16)(r >> 16);
}

__device__ __forceinline__ void async16(const void* g, void* l) {
  __builtin_amdgcn_global_load_lds(
      (const __attribute__((address_space(1))) unsigned int*)g,
      (__attribute__((address_space(3))) unsigned int*)l, 16, 0, 0);
}

__device__ __forceinline__ f32x4 mfma16x16(bf16x4 a, bf16x4 b, f32x4 c) {
#if __has_builtin(__builtin_amdgcn_mfma_f32_16x16x16bf16_1k)
  return __builtin_amdgcn_mfma_f32_16x16x16bf16_1k(a, b, c, 0, 0, 0);
#else
  asm volatile("v_mfma_f32_16x16x16_bf16 %0, %1, %2, %0\n\ts_nop 7\n\ts_nop 7"
               : "+v"(c) : "v"(a), "v"(b));
  return c;
#endif
}

// ---------------- front kernel: pose MLP + x cast + both weight transposes
__global__ void __launch_bounds__(256) front_kernel(
    const float4* __restrict__ x4, u16x4* __restrict__ xh4,
    const float* __restrict__ ang, const float* __restrict__ W1,
    const float* __restrict__ b1, const float* __restrict__ W2,
    const float* __restrict__ b2, float* __restrict__ pose,
    const float* __restrict__ Wqkv, u16* __restrict__ wqkvt,
    const float* __restrict__ Wproj, u16* __restrict__ wprojt) {
  __shared__ float sh[64 * 65];
  const int fb = blockIdx.x, t = threadIdx.x;
  if (fb < 96) {
    float (*hid)[64] = (float (*)[64])sh;
    for (int idx = t; idx < 512; idx += 256) {
      int b = idx >> 6, j = idx & 63;
      float a = b1[j];
#pragma unroll
      for (int i = 0; i < 3; ++i) a += ang[b * 3 + i] * W1[i * 64 + j];
      hid[b][j] = fmaxf(a, 0.f);
    }
    __syncthreads();
    int idx = fb * 256 + t;
    int b = idx / 3072, c = idx - b * 3072;
    float a = b2[c];
#pragma unroll
    for (int j = 0; j < 64; ++j) a += hid[b][j] * W2[j * 3072 + c];
    pose[idx] = a;
  } else if (fb < 1120) {
    const int n4 = 8 * 1024 * 1024 / 4;
    int i = (fb - 96) * 256 + t;
    const int stride = 1024 * 256;
    for (; i < n4; i += stride) {
      float4 v = x4[i];
      u16x4 o;
      o[0] = f2bf(v.x); o[1] = f2bf(v.y); o[2] = f2bf(v.z); o[3] = f2bf(v.w);
      xh4[i] = o;
    }
  } else {
    const float* W; u16* Wt; int Kdim, Ncol, bx, by;
    if (fb < 1888) { W = Wqkv; Wt = wqkvt; Kdim = 1024; Ncol = 3072;
                     int b = fb - 1120; bx = b % 48; by = b / 48; }
    else           { W = Wproj; Wt = wprojt; Kdim = 1024; Ncol = 1024;
                     int b = fb - 1888; bx = b % 16; by = b / 16; }
    float (*tile)[65] = (float (*)[65])sh;
    const int tx = t & 63, ty = t >> 6;
    const int c0 = bx * 64, k0 = by * 64;
#pragma unroll
    for (int rr = 0; rr < 16; ++rr) {
      int row = rr * 4 + ty;
      tile[row][tx] = W[(size_t)(k0 + row) * Ncol + c0 + tx];
    }
    __syncthreads();
#pragma unroll
    for (int rr = 0; rr < 16; ++rr) {
      int row = rr * 4 + ty;
      Wt[(size_t)(c0 + row) * Kdim + k0 + tx] = f2bf(tile[tx][row]);
    }
  }
}

// ---------------- 128x128 GEMM, m97-style high-TLP structure (r13, measured
// best total 194.3us): single-buffer 32 KB LDS, 256 threads (4 waves 2Mx2N),
// per K-tile: {8x gload_lds -> __syncthreads -> frags -> 32 MFMA ->
// __syncthreads}; ~4-5 blocks/CU of cross-block TLP fill the barrier drains.
// T2 swizzle (pre-swizzled global source, same XOR on ds_read; conflicts 0).
// L2 chunk: xcd=blk&7 owns 8 m-panels; c>>3 = n-tile (n-major sweep).
// EPI=0: qkv epilogue (+bias+pose, scatter Q/K [B,H,N,D], Vt [B,H,D,N] bf16)
// EPI=1: proj epilogue (+bias, fp32 row-major out)
template <int EPI>
__global__ void __launch_bounds__(256) gemm97_kernel(
    const u16* __restrict__ A, const u16* __restrict__ Bt,
    const float* __restrict__ bias, const float* __restrict__ pose,
    u16* __restrict__ qout, u16* __restrict__ kout, u16* __restrict__ vtout,
    float* __restrict__ cout, int Kdim, int Ncols) {
  __shared__ u16 ldsA[128 * 64];
  __shared__ u16 ldsB[128 * 64];
  const int t = threadIdx.x, l = t & 63, w = t >> 6;
  const int g = l >> 4, r16 = l & 15;
  const int wr = w >> 1, wc = w & 1;
  const int xk = r16 & 7;
  const int blk = blockIdx.x;
  const int xcd = blk & 7, c = blk >> 3;
  const int m0 = (xcd * 8 + (c & 7)) * 128;   // 8 m-panels per XCD
  const int n0 = (c >> 3) * 128;              // n-major sweep
  const u16* Ab = A + (size_t)m0 * Kdim;
  const u16* Bb = Bt + (size_t)n0 * Kdim;

  f32x4 acc[4][4] = {};
  for (int kt = 0; kt < Kdim; kt += 64) {
#pragma unroll
    for (int ii = 0; ii < 4; ++ii) {
      int idx = ii * 256 + t, row = idx >> 3;
      int seg = (idx & 7) ^ (row & 7);        // pre-swizzled global source (T2)
      async16(Ab + (size_t)row * Kdim + kt + seg * 8, &ldsA[idx * 8]);
    }
#pragma unroll
    for (int ii = 0; ii < 4; ++ii) {
      int idx = ii * 256 + t, row = idx >> 3;
      int seg = (idx & 7) ^ (row & 7);
      async16(Bb + (size_t)row * Kdim + kt + seg * 8, &ldsB[idx * 8]);
    }
    __syncthreads();                           // drains vmcnt + lgkm (compiler)
#pragma unroll
    for (int ks = 0; ks < 2; ++ks) {
      bf16x8 a[4], bb[4];
#pragma unroll
      for (int i = 0; i < 4; ++i)
        a[i] = *(const bf16x8*)&ldsA[(wr * 64 + i * 16 + r16) * 64 + ((ks * 4 + g) ^ xk) * 8];
#pragma unroll
      for (int j = 0; j < 4; ++j)
        bb[j] = *(const bf16x8*)&ldsB[(wc * 64 + j * 16 + r16) * 64 + ((ks * 4 + g) ^ xk) * 8];
#pragma unroll
      for (int i = 0; i < 4; ++i)
#pragma unroll
        for (int j = 0; j < 4; ++j)
          acc[i][j] = __builtin_amdgcn_mfma_f32_16x16x32_bf16(a[i], bb[j], acc[i][j], 0, 0, 0);
    }
    __syncthreads();
  }

#pragma unroll
  for (int i = 0; i < 4; ++i)
#pragma unroll
    for (int j = 0; j < 4; ++j)
#pragma unroll
      for (int r = 0; r < 4; ++r) {
        int row = m0 + wr * 64 + i * 16 + g * 4 + r;
        int col = n0 + wc * 64 + j * 16 + r16;
        float v = acc[i][j][r] + bias[col];
        if (EPI == 0) {
          int b = row >> 10, n = row & 1023;
          v += pose[b * 3072 + col];
          u16 hv = f2bf(v);
          int three = col >> 10, hh = (col >> 6) & 15, d = col & 63;
          size_t bhh = (size_t)(b * 16 + hh);
          if (three == 0)      qout[(bhh * 1024 + n) * 64 + d] = hv;
          else if (three == 1) kout[(bhh * 1024 + n) * 64 + d] = hv;
          else                 vtout[(bhh * 64 + d) * 1024 + n] = hv;
        } else {
          cout[(size_t)row * Ncols + col] = v;
        }
      }
}

// ---------------- attention (r11/r13, measured best-in-total): XCD remap +
// K/V LDS double-buffer + raw-score exp2 softmax + defer-max rescale.
__global__ void __launch_bounds__(256) attn_kernel(
    const u16* __restrict__ Qb, const u16* __restrict__ Kb,
    const u16* __restrict__ Vtb, u16* __restrict__ aout) {
  __shared__ u16 ldsK[2][64][72];
  __shared__ u16 ldsV[2][64][72];
  const int t = threadIdx.x, l = t & 63, w = t >> 6;
  const int g = l >> 4, r16 = l & 15;
  const int blk = blockIdx.x;
  const int bh = blk & 127, qt = blk >> 7;   // XCD-locality remap
  const int b = bh >> 4, h = bh & 15;
  const int q0 = qt * 64 + w * 16;
  const u16* Qp = Qb + ((size_t)bh * 1024 + q0 + r16) * 64;
  bf16x8 qreg0 = *(const bf16x8*)(Qp + g * 8);
  bf16x8 qreg1 = *(const bf16x8*)(Qp + 32 + g * 8);
  const u16* Kbase = Kb + (size_t)bh * 1024 * 64;
  const u16* Vbase = Vtb + (size_t)bh * 64 * 1024;
  const float cexp = 0.18033688f;            // 0.125 * log2(e)

  const int row0 = t >> 3, seg0 = t & 7;
  const int row1 = (256 + t) >> 3, seg1 = t & 7;
  bf16x8 kreg0, kreg1, vreg0, vreg1;
  auto gload = [&](int key0) {
    kreg0 = *(const bf16x8*)(Kbase + (size_t)(key0 + row0) * 64 + seg0 * 8);
    vreg0 = *(const bf16x8*)(Vbase + (size_t)row0 * 1024 + key0 + seg0 * 8);
    kreg1 = *(const bf16x8*)(Kbase + (size_t)(key0 + row1) * 64 + seg1 * 8);
    vreg1 = *(const bf16x8*)(Vbase + (size_t)row1 * 1024 + key0 + seg1 * 8);
  };
  auto lwrite = [&](int buf) {
    *(bf16x8*)&ldsK[buf][row0][seg0 * 8] = kreg0;
    *(bf16x8*)&ldsV[buf][row0][seg0 * 8] = vreg0;
    *(bf16x8*)&ldsK[buf][row1][seg1 * 8] = kreg1;
    *(bf16x8*)&ldsV[buf][row1][seg1 * 8] = vreg1;
  };

  float m = -3e38f, rs = 0.f;
  f32x4 o[4] = {};
  gload(0); lwrite(0);
  __syncthreads();
  int cur = 0;
  for (int kt = 0; kt < 16; ++kt) {
    const bool pf = (kt + 1 < 16);
    if (pf) gload((kt + 1) * 64);
    f32x4 s[4] = {};
#pragma unroll
    for (int f = 0; f < 4; ++f) {
      bf16x8 ak0 = *(const bf16x8*)&ldsK[cur][f * 16 + r16][g * 8];
      s[f] = __builtin_amdgcn_mfma_f32_16x16x32_bf16(ak0, qreg0, s[f], 0, 0, 0);
      bf16x8 ak1 = *(const bf16x8*)&ldsK[cur][f * 16 + r16][32 + g * 8];
      s[f] = __builtin_amdgcn_mfma_f32_16x16x32_bf16(ak1, qreg1, s[f], 0, 0, 0);
    }
    float m01, m23, mt = -3e38f;
#pragma unroll
    for (int f = 0; f < 4; ++f) {
      m01 = fmaxf(s[f][0], s[f][1]);
      m23 = fmaxf(s[f][2], s[f][3]);
      mt = fmaxf(mt, fmaxf(m01, m23));
    }
    mt = fmaxf(mt, __shfl_xor(mt, 16));
    mt = fmaxf(mt, __shfl_xor(mt, 32));
    if (!__all(mt - m <= 64.f)) {
      float mnew = fmaxf(m, mt);
      float alpha = exp2f((m - mnew) * cexp);
      float ar[4];
#pragma unroll
      for (int r = 0; r < 4; ++r) ar[r] = __shfl(alpha, (l & 48) | (g * 4 + r));
#pragma unroll
      for (int nf = 0; nf < 4; ++nf)
#pragma unroll
        for (int r = 0; r < 4; ++r) o[nf][r] *= ar[r];
      rs *= alpha;
      m = mnew;
    }
    float rt = 0.f;
    bf16x4 pa[4];
#pragma unroll
    for (int f = 0; f < 4; ++f) {
#pragma unroll
      for (int r = 0; r < 4; ++r) {
        float p = exp2f((s[f][r] - m) * cexp);
        rt += p;
        pa[f][r] = (short)f2bf(p);
      }
    }
    rt += __shfl_xor(rt, 16);
    rt += __shfl_xor(rt, 32);
    rs += rt;
#pragma unroll
    for (int s4 = 0; s4 < 4; ++s4)
#pragma unroll
      for (int nf = 0; nf < 4; ++nf) {
        bf16x4 bv = *(const bf16x4*)&ldsV[cur][nf * 16 + r16][s4 * 16 + g * 4];
        o[nf] = mfma16x16(pa[s4], bv, o[nf]);
      }
    if (pf) lwrite(cur ^ 1);
    __syncthreads();
    cur ^= 1;
  }
  float rr[4];
#pragma unroll
  for (int r = 0; r < 4; ++r) rr[r] = __shfl(1.0f / rs, (l & 48) | (g * 4 + r));
#pragma unroll
  for (int nf = 0; nf < 4; ++nf)
#pragma unroll
    for (int r = 0; r < 4; ++r) {
      int qq = qt * 64 + w * 16 + g * 4 + r;
      int d = nf * 16 + r16;
      aout[((size_t)b * 1024 + qq) * 1024 + h * 64 + d] = f2bf(o[nf][r] * rr[r]);
    }
}

extern "C" void kernel_launch(void* const* d_in, const int* in_sizes, int n_in,
                              void* d_out, int out_size, void* d_ws, size_t ws_size,
                              hipStream_t stream) {
  (void)in_sizes; (void)n_in; (void)out_size; (void)ws_size;
  const float* x     = (const float*)d_in[0];
  const float* ang   = (const float*)d_in[1];
  const float* Wqkv  = (const float*)d_in[2];
  const float* bqkv  = (const float*)d_in[3];
  const float* W1    = (const float*)d_in[4];
  const float* b1    = (const float*)d_in[5];
  const float* W2    = (const float*)d_in[6];
  const float* b2    = (const float*)d_in[7];
  const float* Wproj = (const float*)d_in[8];
  const float* bproj = (const float*)d_in[9];
  float* out = (float*)d_out;
  char* ws = (char*)d_ws;

  u16* xh     = (u16*)(ws);                                 // 16 MB; reused as attn_out
  u16* wqkvt  = (u16*)(ws + (size_t)16 * 1024 * 1024);      // 6 MB
  u16* wprojt = (u16*)(ws + (size_t)22 * 1024 * 1024);      // 2 MB
  float* pose = (float*)(ws + (size_t)24 * 1024 * 1024);    // 96 KB
  u16* Qb     = (u16*)(ws + (size_t)25 * 1024 * 1024);      // 16 MB
  u16* Kb     = (u16*)(ws + (size_t)41 * 1024 * 1024);      // 16 MB
  u16* Vtb    = (u16*)(ws + (size_t)57 * 1024 * 1024);      // 16 MB

  front_kernel<<<2144, 256, 0, stream>>>((const float4*)x, (u16x4*)xh,
                                         ang, W1, b1, W2, b2, pose,
                                         Wqkv, wqkvt, Wproj, wprojt);
  // QKV: 8 XCD x 8 m-panels x 24 n-tiles = 1536 blocks, ~4-5 resident/CU
  gemm97_kernel<0><<<1536, 256, 0, stream>>>(xh, wqkvt, bqkv, pose,
                                             Qb, Kb, Vtb, nullptr, 1024, 3072);
  attn_kernel<<<2048, 256, 0, stream>>>(Qb, Kb, Vtb, xh);
  // proj: 8 XCD x 8 m-panels x 8 n-tiles = 512 blocks
  gemm97_kernel<1><<<512, 256, 0, stream>>>(xh, wprojt, bproj, nullptr,
                                            nullptr, nullptr, nullptr, out, 1024, 1024);
}

// Round 22
// 193.000 us; speedup vs baseline: 2.3355x; 1.0050x over previous
//
#include <hip/hip_runtime.h>
#include <stdint.h>

typedef unsigned short u16;
typedef short bf16x8 __attribute__((ext_vector_type(8)));
typedef short bf16x4 __attribute__((ext_vector_type(4)));
typedef float f32x4 __attribute__((ext_vector_type(4)));
typedef u16 u16x4 __attribute__((ext_vector_type(4)));

__device__ __forceinline__ u16 f2bf(float f) {
  union { float f; unsigned int u; } v; v.f = f;
  unsigned int r = v.u + 0x7fffu + ((v.u >> 16) & 1u);
  return (u16)(r >> 16);
}

__device__ __forceinline__ void async16(const void* g, void* l) {
  __builtin_amdgcn_global_load_lds(
      (const __attribute__((address_space(1))) unsigned int*)g,
      (__attribute__((address_space(3))) unsigned int*)l, 16, 0, 0);
}

__device__ __forceinline__ f32x4 mfma16x16(bf16x4 a, bf16x4 b, f32x4 c) {
#if __has_builtin(__builtin_amdgcn_mfma_f32_16x16x16bf16_1k)
  return __builtin_amdgcn_mfma_f32_16x16x16bf16_1k(a, b, c, 0, 0, 0);
#else
  asm volatile("v_mfma_f32_16x16x16_bf16 %0, %1, %2, %0\n\ts_nop 7\n\ts_nop 7"
               : "+v"(c) : "v"(a), "v"(b));
  return c;
#endif
}

// ---------------- front kernel: pose MLP + x cast + both weight transposes
__global__ void __launch_bounds__(256) front_kernel(
    const float4* __restrict__ x4, u16x4* __restrict__ xh4,
    const float* __restrict__ ang, const float* __restrict__ W1,
    const float* __restrict__ b1, const float* __restrict__ W2,
    const float* __restrict__ b2, float* __restrict__ pose,
    const float* __restrict__ Wqkv, u16* __restrict__ wqkvt,
    const float* __restrict__ Wproj, u16* __restrict__ wprojt) {
  __shared__ float sh[64 * 65];
  const int fb = blockIdx.x, t = threadIdx.x;
  if (fb < 96) {
    float (*hid)[64] = (float (*)[64])sh;
    for (int idx = t; idx < 512; idx += 256) {
      int b = idx >> 6, j = idx & 63;
      float a = b1[j];
#pragma unroll
      for (int i = 0; i < 3; ++i) a += ang[b * 3 + i] * W1[i * 64 + j];
      hid[b][j] = fmaxf(a, 0.f);
    }
    __syncthreads();
    int idx = fb * 256 + t;
    int b = idx / 3072, c = idx - b * 3072;
    float a = b2[c];
#pragma unroll
    for (int j = 0; j < 64; ++j) a += hid[b][j] * W2[j * 3072 + c];
    pose[idx] = a;
  } else if (fb < 1120) {
    const int n4 = 8 * 1024 * 1024 / 4;
    int i = (fb - 96) * 256 + t;
    const int stride = 1024 * 256;
    for (; i < n4; i += stride) {
      float4 v = x4[i];
      u16x4 o;
      o[0] = f2bf(v.x); o[1] = f2bf(v.y); o[2] = f2bf(v.z); o[3] = f2bf(v.w);
      xh4[i] = o;
    }
  } else {
    const float* W; u16* Wt; int Kdim, Ncol, bx, by;
    if (fb < 1888) { W = Wqkv; Wt = wqkvt; Kdim = 1024; Ncol = 3072;
                     int b = fb - 1120; bx = b % 48; by = b / 48; }
    else           { W = Wproj; Wt = wprojt; Kdim = 1024; Ncol = 1024;
                     int b = fb - 1888; bx = b % 16; by = b / 16; }
    float (*tile)[65] = (float (*)[65])sh;
    const int tx = t & 63, ty = t >> 6;
    const int c0 = bx * 64, k0 = by * 64;
#pragma unroll
    for (int rr = 0; rr < 16; ++rr) {
      int row = rr * 4 + ty;
      tile[row][tx] = W[(size_t)(k0 + row) * Ncol + c0 + tx];
    }
    __syncthreads();
#pragma unroll
    for (int rr = 0; rr < 16; ++rr) {
      int row = rr * 4 + ty;
      Wt[(size_t)(c0 + row) * Kdim + k0 + tx] = f2bf(tile[tx][row]);
    }
  }
}

// ---------------- 128x128 GEMM, m97-style high-TLP structure (r13/r21 best):
// single-buffer 32 KB LDS, 256 threads (4 waves 2Mx2N), T2 swizzle, L2 chunk.
// EPI=0: qkv epilogue (+bias+pose, scatter Q/K [B,H,N,D], Vt [B,H,D,N] bf16)
// EPI=1: proj epilogue (+bias, fp32 row-major out)
template <int EPI>
__global__ void __launch_bounds__(256) gemm97_kernel(
    const u16* __restrict__ A, const u16* __restrict__ Bt,
    const float* __restrict__ bias, const float* __restrict__ pose,
    u16* __restrict__ qout, u16* __restrict__ kout, u16* __restrict__ vtout,
    float* __restrict__ cout, int Kdim, int Ncols) {
  __shared__ u16 ldsA[128 * 64];
  __shared__ u16 ldsB[128 * 64];
  const int t = threadIdx.x, l = t & 63, w = t >> 6;
  const int g = l >> 4, r16 = l & 15;
  const int wr = w >> 1, wc = w & 1;
  const int xk = r16 & 7;
  const int blk = blockIdx.x;
  const int xcd = blk & 7, c = blk >> 3;
  const int m0 = (xcd * 8 + (c & 7)) * 128;   // 8 m-panels per XCD
  const int n0 = (c >> 3) * 128;              // n-major sweep
  const u16* Ab = A + (size_t)m0 * Kdim;
  const u16* Bb = Bt + (size_t)n0 * Kdim;

  f32x4 acc[4][4] = {};
  for (int kt = 0; kt < Kdim; kt += 64) {
#pragma unroll
    for (int ii = 0; ii < 4; ++ii) {
      int idx = ii * 256 + t, row = idx >> 3;
      int seg = (idx & 7) ^ (row & 7);        // pre-swizzled global source (T2)
      async16(Ab + (size_t)row * Kdim + kt + seg * 8, &ldsA[idx * 8]);
    }
#pragma unroll
    for (int ii = 0; ii < 4; ++ii) {
      int idx = ii * 256 + t, row = idx >> 3;
      int seg = (idx & 7) ^ (row & 7);
      async16(Bb + (size_t)row * Kdim + kt + seg * 8, &ldsB[idx * 8]);
    }
    __syncthreads();
#pragma unroll
    for (int ks = 0; ks < 2; ++ks) {
      bf16x8 a[4], bb[4];
#pragma unroll
      for (int i = 0; i < 4; ++i)
        a[i] = *(const bf16x8*)&ldsA[(wr * 64 + i * 16 + r16) * 64 + ((ks * 4 + g) ^ xk) * 8];
#pragma unroll
      for (int j = 0; j < 4; ++j)
        bb[j] = *(const bf16x8*)&ldsB[(wc * 64 + j * 16 + r16) * 64 + ((ks * 4 + g) ^ xk) * 8];
#pragma unroll
      for (int i = 0; i < 4; ++i)
#pragma unroll
        for (int j = 0; j < 4; ++j)
          acc[i][j] = __builtin_amdgcn_mfma_f32_16x16x32_bf16(a[i], bb[j], acc[i][j], 0, 0, 0);
    }
    __syncthreads();
  }

#pragma unroll
  for (int i = 0; i < 4; ++i)
#pragma unroll
    for (int j = 0; j < 4; ++j)
#pragma unroll
      for (int r = 0; r < 4; ++r) {
        int row = m0 + wr * 64 + i * 16 + g * 4 + r;
        int col = n0 + wc * 64 + j * 16 + r16;
        float v = acc[i][j][r] + bias[col];
        if (EPI == 0) {
          int b = row >> 10, n = row & 1023;
          v += pose[b * 3072 + col];
          u16 hv = f2bf(v);
          int three = col >> 10, hh = (col >> 6) & 15, d = col & 63;
          size_t bhh = (size_t)(b * 16 + hh);
          if (three == 0)      qout[(bhh * 1024 + n) * 64 + d] = hv;
          else if (three == 1) kout[(bhh * 1024 + n) * 64 + d] = hv;
          else                 vtout[(bhh * 64 + d) * 1024 + n] = hv;
        } else {
          cout[(size_t)row * Ncols + col] = v;
        }
      }
}

// ---------------- attention r22: 512 threads / 8 waves per block, shared
// K/V staging (one 64-tile per block, each wave its own 16 q-rows).
// LDS unchanged (36 KB, padded [64][72], linear rw) -> 4 blocks/CU x 8 waves
// = 32 waves/CU = 100% occupancy (vs 16 waves at r21's 256-thr blocks) --
// attacks the measured latency-bound regime (r19/r20). Per-wave pipeline
// byte-identical to r21 (exp2 + defer-max + butterfly rowsum + scalar f2bf).
// Staging: 512 threads x one 16B chunk each for K and V (exactly one
// 64x64 tile per matrix). Grid 1024: bh = blk&127 (XCD remap), qt = blk>>7.
__global__ void __launch_bounds__(512) attn_kernel(
    const u16* __restrict__ Qb, const u16* __restrict__ Kb,
    const u16* __restrict__ Vtb, u16* __restrict__ aout) {
  __shared__ u16 ldsK[2][64][72];
  __shared__ u16 ldsV[2][64][72];
  const int t = threadIdx.x, l = t & 63, w = t >> 6;   // w in 0..7
  const int g = l >> 4, r16 = l & 15;
  const int blk = blockIdx.x;
  const int bh = blk & 127, qt = blk >> 7;   // qt in 0..7; XCD remap kept
  const int b = bh >> 4, h = bh & 15;
  const int q0 = qt * 128 + w * 16;          // 128 q-rows per block
  const u16* Qp = Qb + ((size_t)bh * 1024 + q0 + r16) * 64;
  bf16x8 qreg0 = *(const bf16x8*)(Qp + g * 8);
  bf16x8 qreg1 = *(const bf16x8*)(Qp + 32 + g * 8);
  const u16* Kbase = Kb + (size_t)bh * 1024 * 64;
  const u16* Vbase = Vtb + (size_t)bh * 64 * 1024;
  const float cexp = 0.18033688f;            // 0.125 * log2(e)

  // 512 threads: one 16B chunk per thread per matrix = full 64x64 tile
  const int row0 = t >> 3, seg0 = t & 7;
  bf16x8 kreg0, vreg0;
  auto gload = [&](int key0) {
    kreg0 = *(const bf16x8*)(Kbase + (size_t)(key0 + row0) * 64 + seg0 * 8);
    vreg0 = *(const bf16x8*)(Vbase + (size_t)row0 * 1024 + key0 + seg0 * 8);
  };
  auto lwrite = [&](int buf) {
    *(bf16x8*)&ldsK[buf][row0][seg0 * 8] = kreg0;
    *(bf16x8*)&ldsV[buf][row0][seg0 * 8] = vreg0;
  };

  float m = -3e38f, rs = 0.f;
  f32x4 o[4] = {};
  gload(0); lwrite(0);
  __syncthreads();
  int cur = 0;
  for (int kt = 0; kt < 16; ++kt) {
    const bool pf = (kt + 1 < 16);
    if (pf) gload((kt + 1) * 64);
    f32x4 s[4] = {};
#pragma unroll
    for (int f = 0; f < 4; ++f) {
      bf16x8 ak0 = *(const bf16x8*)&ldsK[cur][f * 16 + r16][g * 8];
      s[f] = __builtin_amdgcn_mfma_f32_16x16x32_bf16(ak0, qreg0, s[f], 0, 0, 0);
      bf16x8 ak1 = *(const bf16x8*)&ldsK[cur][f * 16 + r16][32 + g * 8];
      s[f] = __builtin_amdgcn_mfma_f32_16x16x32_bf16(ak1, qreg1, s[f], 0, 0, 0);
    }
    float m01, m23, mt = -3e38f;
#pragma unroll
    for (int f = 0; f < 4; ++f) {
      m01 = fmaxf(s[f][0], s[f][1]);
      m23 = fmaxf(s[f][2], s[f][3]);
      mt = fmaxf(mt, fmaxf(m01, m23));
    }
    mt = fmaxf(mt, __shfl_xor(mt, 16));
    mt = fmaxf(mt, __shfl_xor(mt, 32));
    if (!__all(mt - m <= 64.f)) {
      float mnew = fmaxf(m, mt);
      float alpha = exp2f((m - mnew) * cexp);
      float ar[4];
#pragma unroll
      for (int r = 0; r < 4; ++r) ar[r] = __shfl(alpha, (l & 48) | (g * 4 + r));
#pragma unroll
      for (int nf = 0; nf < 4; ++nf)
#pragma unroll
        for (int r = 0; r < 4; ++r) o[nf][r] *= ar[r];
      rs *= alpha;
      m = mnew;
    }
    float rt = 0.f;
    bf16x4 pa[4];
#pragma unroll
    for (int f = 0; f < 4; ++f) {
#pragma unroll
      for (int r = 0; r < 4; ++r) {
        float p = exp2f((s[f][r] - m) * cexp);
        rt += p;
        pa[f][r] = (short)f2bf(p);
      }
    }
    rt += __shfl_xor(rt, 16);
    rt += __shfl_xor(rt, 32);
    rs += rt;
#pragma unroll
    for (int s4 = 0; s4 < 4; ++s4)
#pragma unroll
      for (int nf = 0; nf < 4; ++nf) {
        bf16x4 bv = *(const bf16x4*)&ldsV[cur][nf * 16 + r16][s4 * 16 + g * 4];
        o[nf] = mfma16x16(pa[s4], bv, o[nf]);
      }
    if (pf) lwrite(cur ^ 1);
    __syncthreads();
    cur ^= 1;
  }
  float rr[4];
#pragma unroll
  for (int r = 0; r < 4; ++r) rr[r] = __shfl(1.0f / rs, (l & 48) | (g * 4 + r));
#pragma unroll
  for (int nf = 0; nf < 4; ++nf)
#pragma unroll
    for (int r = 0; r < 4; ++r) {
      int qq = q0 + g * 4 + r;
      int d = nf * 16 + r16;
      aout[((size_t)b * 1024 + qq) * 1024 + h * 64 + d] = f2bf(o[nf][r] * rr[r]);
    }
}

extern "C" void kernel_launch(void* const* d_in, const int* in_sizes, int n_in,
                              void* d_out, int out_size, void* d_ws, size_t ws_size,
                              hipStream_t stream) {
  (void)in_sizes; (void)n_in; (void)out_size; (void)ws_size;
  const float* x     = (const float*)d_in[0];
  const float* ang   = (const float*)d_in[1];
  const float* Wqkv  = (const float*)d_in[2];
  const float* bqkv  = (const float*)d_in[3];
  const float* W1    = (const float*)d_in[4];
  const float* b1    = (const float*)d_in[5];
  const float* W2    = (const float*)d_in[6];
  const float* b2    = (const float*)d_in[7];
  const float* Wproj = (const float*)d_in[8];
  const float* bproj = (const float*)d_in[9];
  float* out = (float*)d_out;
  char* ws = (char*)d_ws;

  u16* xh     = (u16*)(ws);                                 // 16 MB; reused as attn_out
  u16* wqkvt  = (u16*)(ws + (size_t)16 * 1024 * 1024);      // 6 MB
  u16* wprojt = (u16*)(ws + (size_t)22 * 1024 * 1024);      // 2 MB
  float* pose = (float*)(ws + (size_t)24 * 1024 * 1024);    // 96 KB
  u16* Qb     = (u16*)(ws + (size_t)25 * 1024 * 1024);      // 16 MB
  u16* Kb     = (u16*)(ws + (size_t)41 * 1024 * 1024);      // 16 MB
  u16* Vtb    = (u16*)(ws + (size_t)57 * 1024 * 1024);      // 16 MB

  front_kernel<<<2144, 256, 0, stream>>>((const float4*)x, (u16x4*)xh,
                                         ang, W1, b1, W2, b2, pose,
                                         Wqkv, wqkvt, Wproj, wprojt);
  // QKV: 8 XCD x 8 m-panels x 24 n-tiles = 1536 blocks
  gemm97_kernel<0><<<1536, 256, 0, stream>>>(xh, wqkvt, bqkv, pose,
                                             Qb, Kb, Vtb, nullptr, 1024, 3072);
  // attn: 8 q-tiles of 128 x 128 bh = 1024 blocks, 512 thr (32 waves/CU)
  attn_kernel<<<1024, 512, 0, stream>>>(Qb, Kb, Vtb, xh);
  // proj: 8 XCD x 8 m-panels x 8 n-tiles = 512 blocks
  gemm97_kernel<1><<<512, 256, 0, stream>>>(xh, wprojt, bproj, nullptr,
                                            nullptr, nullptr, nullptr, out, 1024, 1024);
}